// Round 19
// baseline (144298.755 us; speedup 1.0000x reference)
//
#include <hip/hip_runtime.h>
#include <stdint.h>

typedef unsigned long long u64;
typedef float f32x32 __attribute__((ext_vector_type(32)));
typedef float f32x16 __attribute__((ext_vector_type(16)));
typedef float f32x4  __attribute__((ext_vector_type(4)));

#define T_TOTAL 65536
#define ISZ 256
#define HSZ 512
#define NWORK 16
#define SLICE 32   // HSZ / NWORK
#define NTHR 512   // 8 waves: even 2/SIMD split -> 256-reg budget (R10 lesson)

// LDS skew (word index): +4 words per row -> max 2-way bank aliasing (free).
__device__ __forceinline__ int HSW(int i) { return i + ((i >> 5) << 2); }  // rows of 32
__device__ __forceinline__ int XSW(int i) { return i + ((i >> 4) << 2); }  // rows of 16

struct Ctl { int grank; int chosen; int fastctr; int done; int slowctr; int pad[11]; };

__device__ __forceinline__ f32x4 xload_asm(const float* p) {
  f32x4 r;
  asm volatile("global_load_dwordx4 %0, %1, off" : "=v"(r) : "v"(p));
  return r;
}

// ---------------------------------------------------------------------------
// Persistent fused GRU scan, 16 blocks x 512 threads.
// Sync primitives (R14-proven): publish = 8B store sc0 (write-through vL1 ->
// XCD L2, immediate post-butterfly = earliest chain edge); poll = buffer_inv;
// s_waitcnt; L2 loads (sticky RMW fallback).
//
// R17/R18 intent, compile-fixed (R18: float4 struct can't bind as "v" asm
// operand -> use f32x4 ext_vector): detection cheap & low-contention.
// ONE polling wave per block (wave 0; each lane owns one 128B line = 8 slots,
// 8 loads in flight, one vmcnt(0)) -> per round: 1 buffer_inv + 64 line-loads
// per block instead of 512 invs + 8192 loads chip-wide (R14). Waves 1-6:
// zero vmem. Wave 7: x stager (counted vmcnt, 2-deep reg pipeline) + out[]
// rows from h_lds post-B2 (out row s-1 == h_s; no handoff, no race).
//
// ONE raw barrier (B2, lgkmcnt-only) per step. Safety:
//  - h_lds[cur] rewrite at s+2 (wave0, pre-B2(s+2)) is post-B2(s+1), and any
//    wave arrives at B2(s+1) only after finishing matvec(s) -> no overlap.
//  - x_lds[nxt] commit@s pre-B2(s); reads@s+1 pre-B2(s+1); next commit@s+2
//    post-B2(s+1). Disjoint.
//  - Slot parity ring: block A publishes tag s+1 (post-B2(s)) only after its
//    wave0 saw tag s on ALL slots, which requires every block D published
//    tag s (post-D's B2(s-1)), i.e. D finished reading tag s-1 from the
//    parity bank A now overwrites. Same argument as R6/R8.
// Spin fuse (fail visibly, never wedge); SLOW fallback: R2-proven protocol.
// ---------------------------------------------------------------------------
__global__ __launch_bounds__(NTHR, 1) void gru_fused(
    const float* __restrict__ xs, const float* __restrict__ w_ih,
    const float* __restrict__ w_hh, const float* __restrict__ bias,
    const float* __restrict__ bias_n, u64* __restrict__ hslot,
    Ctl* __restrict__ ctl, float* __restrict__ out) {
  const int tid = threadIdx.x;
  const int seg = tid & 15;   // K-segment: h[32*seg..+32), x[16*seg..+16)
  const int rg  = tid >> 4;   // unit within slice (0..31)

  __shared__ int s_role, s_fast;
  __shared__ __align__(16) float x_lds[2][320];
  __shared__ __align__(16) float h_lds[2][576];

  // ---- election: verify 16 blocks on one XCD, else agent-scope fallback
  if (tid == 0) {
    unsigned xcc = 0;
    asm volatile("s_getreg_b32 %0, hwreg(HW_REG_XCC_ID)" : "=s"(xcc));
    long long eb = 100000000;
    int rank = __hip_atomic_fetch_add(&ctl->grank, 1, __ATOMIC_RELAXED,
                                      __HIP_MEMORY_SCOPE_AGENT);
    if (rank == 0)
      __hip_atomic_store(&ctl->chosen, (int)xcc + 1, __ATOMIC_RELEASE,
                         __HIP_MEMORY_SCOPE_AGENT);
    int chosen;
    do { chosen = __hip_atomic_load(&ctl->chosen, __ATOMIC_ACQUIRE,
                                    __HIP_MEMORY_SCOPE_AGENT); }
    while (chosen == 0 && --eb > 0);
    int fr = -1;
    if ((int)xcc == chosen - 1)
      fr = __hip_atomic_fetch_add(&ctl->fastctr, 1, __ATOMIC_RELAXED,
                                  __HIP_MEMORY_SCOPE_AGENT);
    __hip_atomic_fetch_add(&ctl->done, 1, __ATOMIC_ACQ_REL,
                           __HIP_MEMORY_SCOPE_AGENT);
    int dn;
    do { dn = __hip_atomic_load(&ctl->done, __ATOMIC_ACQUIRE,
                                __HIP_MEMORY_SCOPE_AGENT); }
    while (dn < (int)gridDim.x && --eb > 0);
    int fc = __hip_atomic_load(&ctl->fastctr, __ATOMIC_ACQUIRE,
                               __HIP_MEMORY_SCOPE_AGENT);
    int fast = (fc >= NWORK && dn >= (int)gridDim.x) ? 1 : 0;
    int role = -1;
    if (fast) {
      if (fr >= 0 && fr < NWORK) role = fr;
    } else {
      int sr = __hip_atomic_fetch_add(&ctl->slowctr, 1, __ATOMIC_RELAXED,
                                      __HIP_MEMORY_SCOPE_AGENT);
      if (sr < NWORK) role = sr;
    }
    s_role = role; s_fast = fast;
  }
  __syncthreads();
  const int role = s_role;   // uniform per block
  const int fast = s_fast;
  if (role < 0) return;      // whole block exits together

  // ---- weights into registers (ext_vector, static indexing; R8-proven) ----
  const int myunit = role * SLICE + rg;
  f32x32 wh0, wh1, wh2;
  f32x16 wi0, wi1, wi2;
  {
    const float* h0 = w_hh + (size_t)(0 * HSZ + myunit) * HSZ + seg * 32;
    const float* h1 = w_hh + (size_t)(1 * HSZ + myunit) * HSZ + seg * 32;
    const float* h2 = w_hh + (size_t)(2 * HSZ + myunit) * HSZ + seg * 32;
#pragma unroll
    for (int u = 0; u < 8; ++u) {
      float4 a = *(const float4*)(h0 + u * 4);
      float4 b = *(const float4*)(h1 + u * 4);
      float4 c = *(const float4*)(h2 + u * 4);
      wh0[u*4+0]=a.x; wh0[u*4+1]=a.y; wh0[u*4+2]=a.z; wh0[u*4+3]=a.w;
      wh1[u*4+0]=b.x; wh1[u*4+1]=b.y; wh1[u*4+2]=b.z; wh1[u*4+3]=b.w;
      wh2[u*4+0]=c.x; wh2[u*4+1]=c.y; wh2[u*4+2]=c.z; wh2[u*4+3]=c.w;
    }
    const float* i0 = w_ih + (size_t)(0 * HSZ + myunit) * ISZ + seg * 16;
    const float* i1 = w_ih + (size_t)(1 * HSZ + myunit) * ISZ + seg * 16;
    const float* i2 = w_ih + (size_t)(2 * HSZ + myunit) * ISZ + seg * 16;
#pragma unroll
    for (int u = 0; u < 4; ++u) {
      float4 a = *(const float4*)(i0 + u * 4);
      float4 b = *(const float4*)(i1 + u * 4);
      float4 c = *(const float4*)(i2 + u * 4);
      wi0[u*4+0]=a.x; wi0[u*4+1]=a.y; wi0[u*4+2]=a.z; wi0[u*4+3]=a.w;
      wi1[u*4+0]=b.x; wi1[u*4+1]=b.y; wi1[u*4+2]=b.z; wi1[u*4+3]=b.w;
      wi2[u*4+0]=c.x; wi2[u*4+1]=c.y; wi2[u*4+2]=c.z; wi2[u*4+3]=c.w;
    }
  }
  const float br  = bias[myunit];
  const float bz  = bias[HSZ + myunit];
  const float bnn = bias[2 * HSZ + myunit];
  const float bn2 = bias_n[myunit];

  long long budget = 20000000;  // spin fuse (fail visibly, never wedge)

  if (!fast) {
    // ---- SLOW fallback: R2-proven full-tag agent-scope protocol ----
    float hprev = 0.f;
    for (int s = 0; s < T_TOTAL; ++s) {
      if (tid < 64) {
        float4 v = *(const float4*)(xs + (size_t)s * ISZ + tid * 4);
        *(float4*)&x_lds[0][XSW(tid * 4)] = v;
      }
      __syncthreads();
      float a0 = 0.f, a1 = 0.f, a2 = 0.f, a3 = 0.f;
#pragma unroll
      for (int u = 0; u < 4; ++u) {
        float4 xv = *(const float4*)&x_lds[0][XSW(seg * 16 + u * 4)];
        a0 += wi0[u*4+0]*xv.x + wi0[u*4+1]*xv.y + wi0[u*4+2]*xv.z + wi0[u*4+3]*xv.w;
        a1 += wi1[u*4+0]*xv.x + wi1[u*4+1]*xv.y + wi1[u*4+2]*xv.z + wi1[u*4+3]*xv.w;
        a2 += wi2[u*4+0]*xv.x + wi2[u*4+1]*xv.y + wi2[u*4+2]*xv.z + wi2[u*4+3]*xv.w;
      }
      const int cur = s & 1, nxt = cur ^ 1;
      u64 q0;
      do {
        q0 = __hip_atomic_load(&hslot[(size_t)cur * 1024 + 2 * tid],
                               __ATOMIC_ACQUIRE, __HIP_MEMORY_SCOPE_AGENT);
      } while ((unsigned)(q0 >> 32) != (unsigned)s && --budget > 0);
      h_lds[cur][HSW(tid)] = __uint_as_float((unsigned)q0);
      __syncthreads();
#pragma unroll
      for (int u = 0; u < 8; ++u) {
        float4 hv = *(const float4*)&h_lds[cur][HSW(seg * 32 + u * 4)];
        a0 += wh0[u*4+0]*hv.x + wh0[u*4+1]*hv.y + wh0[u*4+2]*hv.z + wh0[u*4+3]*hv.w;
        a1 += wh1[u*4+0]*hv.x + wh1[u*4+1]*hv.y + wh1[u*4+2]*hv.z + wh1[u*4+3]*hv.w;
        a3 += wh2[u*4+0]*hv.x + wh2[u*4+1]*hv.y + wh2[u*4+2]*hv.z + wh2[u*4+3]*hv.w;
      }
#pragma unroll
      for (int p = 0; p < 4; ++p) {
        int m = 1 << p;
        a0 += __shfl_xor(a0, m, 64);
        a1 += __shfl_xor(a1, m, 64);
        a2 += __shfl_xor(a2, m, 64);
        a3 += __shfl_xor(a3, m, 64);
      }
      if (seg == 0) {
        float r  = 1.f / (1.f + __expf(-(br + a0)));
        float z  = 1.f / (1.f + __expf(-(bz + a1)));
        float tv = bnn + a2 + r * (a3 + bn2);
        float nn = 1.f - 2.f / (__expf(2.f * tv) + 1.f);
        float hold = h_lds[cur][HSW(myunit)];
        float hnew = nn + z * (hold - nn);
        __hip_atomic_store(&hslot[(size_t)nxt * 1024 + 2 * myunit],
                           ((u64)(unsigned)(s + 1) << 32) | (u64)__float_as_uint(hnew),
                           __ATOMIC_RELEASE, __HIP_MEMORY_SCOPE_AGENT);
        out[(size_t)HSZ + (size_t)s * HSZ + myunit] = hnew;
        hprev = hnew;
      }
      __syncthreads();
    }
    if (seg == 0) out[myunit] = hprev;
    return;
  }

  // ---- FAST path: wave roles. wave0 = sole poller (8 slots/lane from one
  // 128B line); waves 1-6 = pure compute; wave 7 = x stager + out writer. ----
  const bool is_w0 = (tid < 64);
  const bool is_w7 = (tid >= 448);
  const int  wl    = tid & 63;

  // Prologue (wave 7): x[0] -> LDS; issue x[1], x[2] (2-deep asm pipeline).
  f32x4 xA{}, xB{};
  if (is_w7) {
    float4 t0 = *(const float4*)(xs + wl * 4);
    *(float4*)&x_lds[0][XSW(wl * 4)] = t0;
    xA = xload_asm(xs + (size_t)1 * ISZ + wl * 4);
    xB = xload_asm(xs + (size_t)2 * ISZ + wl * 4);
  }
  __syncthreads();

  int sticky = 0;

  for (int s = 0; s < T_TOTAL; ++s) {
    const int cur = s & 1, nxt = cur ^ 1;
    // Each wave-0 lane's 128B line base (16 u64 = 8 slots of 16B stride).
    u64* pbase = hslot + (size_t)cur * 1024 + 16 * wl;

    // 1) Wave 0: speculative poll round issued BEFORE ig-dots.
    u64 q0=0,q1=0,q2=0,q3=0,q4=0,q5=0,q6=0,q7=0;
    if (is_w0 && !sticky) {
      asm volatile("buffer_inv\n\t"
                   "s_waitcnt vmcnt(0)\n\t"
                   "global_load_dwordx2 %0, %8, off offset:0   sc0 nt\n\t"
                   "global_load_dwordx2 %1, %8, off offset:16  sc0 nt\n\t"
                   "global_load_dwordx2 %2, %8, off offset:32  sc0 nt\n\t"
                   "global_load_dwordx2 %3, %8, off offset:48  sc0 nt\n\t"
                   "global_load_dwordx2 %4, %8, off offset:64  sc0 nt\n\t"
                   "global_load_dwordx2 %5, %8, off offset:80  sc0 nt\n\t"
                   "global_load_dwordx2 %6, %8, off offset:96  sc0 nt\n\t"
                   "global_load_dwordx2 %7, %8, off offset:112 sc0 nt"
                   : "=&v"(q0),"=&v"(q1),"=&v"(q2),"=&v"(q3),
                     "=&v"(q4),"=&v"(q5),"=&v"(q6),"=&v"(q7)
                   : "v"(pbase)
                   : "memory");
    }

    // 2) All lanes: input-side gate dots (LDS only). a3 = hidden n part.
    float a0 = 0.f, a1 = 0.f, a2 = 0.f, a3 = 0.f;
#pragma unroll
    for (int u = 0; u < 4; ++u) {
      float4 xv = *(const float4*)&x_lds[cur][XSW(seg * 16 + u * 4)];
      a0 += wi0[u*4+0]*xv.x + wi0[u*4+1]*xv.y + wi0[u*4+2]*xv.z + wi0[u*4+3]*xv.w;
      a1 += wi1[u*4+0]*xv.x + wi1[u*4+1]*xv.y + wi1[u*4+2]*xv.z + wi1[u*4+3]*xv.w;
      a2 += wi2[u*4+0]*xv.x + wi2[u*4+1]*xv.y + wi2[u*4+2]*xv.z + wi2[u*4+3]*xv.w;
    }

    // 3) Wave 0: finish/iterate detection; write 8 h values to LDS.
    if (is_w0) {
      if (!sticky) {
        asm volatile("s_waitcnt vmcnt(0)" ::: "memory");
        int rounds = 0;
        const unsigned sv = (unsigned)s;
        while (((unsigned)(q0 >> 32) != sv) | ((unsigned)(q1 >> 32) != sv) |
               ((unsigned)(q2 >> 32) != sv) | ((unsigned)(q3 >> 32) != sv) |
               ((unsigned)(q4 >> 32) != sv) | ((unsigned)(q5 >> 32) != sv) |
               ((unsigned)(q6 >> 32) != sv) | ((unsigned)(q7 >> 32) != sv)) {
          asm volatile("buffer_inv\n\t"
                       "s_waitcnt vmcnt(0)\n\t"
                       "global_load_dwordx2 %0, %8, off offset:0   sc0 nt\n\t"
                       "global_load_dwordx2 %1, %8, off offset:16  sc0 nt\n\t"
                       "global_load_dwordx2 %2, %8, off offset:32  sc0 nt\n\t"
                       "global_load_dwordx2 %3, %8, off offset:48  sc0 nt\n\t"
                       "global_load_dwordx2 %4, %8, off offset:64  sc0 nt\n\t"
                       "global_load_dwordx2 %5, %8, off offset:80  sc0 nt\n\t"
                       "global_load_dwordx2 %6, %8, off offset:96  sc0 nt\n\t"
                       "global_load_dwordx2 %7, %8, off offset:112 sc0 nt\n\t"
                       "s_waitcnt vmcnt(0)"
                       : "=&v"(q0),"=&v"(q1),"=&v"(q2),"=&v"(q3),
                         "=&v"(q4),"=&v"(q5),"=&v"(q6),"=&v"(q7)
                       : "v"(pbase)
                       : "memory");
          if (++rounds >= 64) { sticky = 1; break; }
          if (--budget <= 0) break;
        }
      }
      if (sticky) {  // R8-proven TCC RMW poll per slot (correctness net)
        u64 zero = 0;
        u64 qq;
#pragma unroll
        for (int k = 0; k < 8; ++k) {
          u64* pk = pbase + 2 * k;
          for (;;) {
            asm volatile("global_atomic_add_x2 %0, %1, %2, off sc0\n\t"
                         "s_waitcnt vmcnt(0)"
                         : "=&v"(qq) : "v"(pk), "v"(zero) : "memory");
            if ((unsigned)(qq >> 32) == (unsigned)s) break;
            if (--budget <= 0) break;
          }
          switch (k) {  // keep q0..q7 in named regs (no dynamic indexing)
            case 0: q0 = qq; break; case 1: q1 = qq; break;
            case 2: q2 = qq; break; case 3: q3 = qq; break;
            case 4: q4 = qq; break; case 5: q5 = qq; break;
            case 6: q6 = qq; break; case 7: q7 = qq; break;
          }
        }
      }
      const int hb = 8 * wl;  // this lane's 8 h values -> h_lds
      h_lds[cur][HSW(hb + 0)] = __uint_as_float((unsigned)q0);
      h_lds[cur][HSW(hb + 1)] = __uint_as_float((unsigned)q1);
      h_lds[cur][HSW(hb + 2)] = __uint_as_float((unsigned)q2);
      h_lds[cur][HSW(hb + 3)] = __uint_as_float((unsigned)q3);
      h_lds[cur][HSW(hb + 4)] = __uint_as_float((unsigned)q4);
      h_lds[cur][HSW(hb + 5)] = __uint_as_float((unsigned)q5);
      h_lds[cur][HSW(hb + 6)] = __uint_as_float((unsigned)q6);
      h_lds[cur][HSW(hb + 7)] = __uint_as_float((unsigned)q7);
    }

    // 4) Wave 7: commit x[s+1] (counted vmcnt; per-step vmem = 1 xload +
    //    2 out-stores), then issue x[s+3].
    if (is_w7) {
      if (s == 0 || s == 1) asm volatile("s_waitcnt vmcnt(1)" ::: "memory");
      else if (s == 2)      asm volatile("s_waitcnt vmcnt(3)" ::: "memory");
      else                  asm volatile("s_waitcnt vmcnt(5)" ::: "memory");
      int srow = (s + 3 < T_TOTAL) ? (s + 3) : (T_TOTAL - 1);
      if ((s & 1) == 0) {
        *(f32x4*)&x_lds[nxt][XSW(wl * 4)] = xA;
        xA = xload_asm(xs + (size_t)srow * ISZ + wl * 4);
      } else {
        *(f32x4*)&x_lds[nxt][XSW(wl * 4)] = xB;
        xB = xload_asm(xs + (size_t)srow * ISZ + wl * 4);
      }
    }

    // B2: LDS-only barrier (no vmcnt drain).
    asm volatile("s_waitcnt lgkmcnt(0)\n\ts_barrier" ::: "memory");

    // 5) Wave 7: out row s-1 = h_s straight from h_lds (fire-and-forget).
    //    f32x4 ext_vector operands (float4 struct can't bind to "v" — R18).
    if (is_w7 && s > 0) {
      f32x4 o0 = *(const f32x4*)&h_lds[cur][HSW(wl * 8)];
      f32x4 o1 = *(const f32x4*)&h_lds[cur][HSW(wl * 8 + 4)];
      float* po = out + HSZ + (size_t)(s - 1) * HSZ + wl * 8;
      asm volatile("global_store_dwordx4 %0, %1, off\n\t"
                   "global_store_dwordx4 %2, %3, off"
                   :: "v"(po), "v"(o0), "v"(po + 4), "v"(o1) : "memory");
    }

    // 6) Hidden-side dots (critical chain) + butterfly (sums in all lanes).
#pragma unroll
    for (int u = 0; u < 8; ++u) {
      float4 hv = *(const float4*)&h_lds[cur][HSW(seg * 32 + u * 4)];
      a0 += wh0[u*4+0]*hv.x + wh0[u*4+1]*hv.y + wh0[u*4+2]*hv.z + wh0[u*4+3]*hv.w;
      a1 += wh1[u*4+0]*hv.x + wh1[u*4+1]*hv.y + wh1[u*4+2]*hv.z + wh1[u*4+3]*hv.w;
      a3 += wh2[u*4+0]*hv.x + wh2[u*4+1]*hv.y + wh2[u*4+2]*hv.z + wh2[u*4+3]*hv.w;
    }
#pragma unroll
    for (int p = 0; p < 4; ++p) {
      int m = 1 << p;
      a0 += __shfl_xor(a0, m, 64);
      a1 += __shfl_xor(a1, m, 64);
      a2 += __shfl_xor(a2, m, 64);
      a3 += __shfl_xor(a3, m, 64);
    }

    // 7) Epilogue on seg0: publish IMMEDIATELY (sc0 L2 store, chain edge).
    if (seg == 0) {
      float r  = 1.f / (1.f + __expf(-(br + a0)));
      float z  = 1.f / (1.f + __expf(-(bz + a1)));
      float tv = bnn + a2 + r * (a3 + bn2);
      float nn = 1.f - 2.f / (__expf(2.f * tv) + 1.f);  // tanh, exact limits
      float hold = h_lds[cur][HSW(myunit)];
      float hnew = nn + z * (hold - nn);
      u64 pw = ((u64)(unsigned)(s + 1) << 32) | (u64)__float_as_uint(hnew);
      u64* pp = &hslot[(size_t)nxt * 1024 + 2 * myunit];
      asm volatile("global_store_dwordx2 %0, %1, off sc0"
                   :: "v"(pp), "v"(pw) : "memory");
      if (s == T_TOTAL - 1) {  // one-time: row T-1 + final state
        out[(size_t)HSZ + (size_t)s * HSZ + myunit] = hnew;
        out[myunit] = hnew;
      }
    }
  }
}

// ---------------------------------------------------------------------------
extern "C" void kernel_launch(void* const* d_in, const int* in_sizes, int n_in,
                              void* d_out, int out_size, void* d_ws, size_t ws_size,
                              hipStream_t stream) {
  const float* xs     = (const float*)d_in[0];
  const float* w_ih   = (const float*)d_in[1];
  const float* w_hh   = (const float*)d_in[2];
  const float* bias   = (const float*)d_in[3];
  const float* bias_n = (const float*)d_in[4];
  float* out   = (float*)d_out;
  u64*   hslot = (u64*)d_ws;                    // [2][512] padded slots = 16 KB
  Ctl*   ctl   = (Ctl*)((char*)d_ws + 16384);   // election control

  hipMemsetAsync(d_ws, 0, 16384 + 256, stream); // tags=0 => h_0 = 0; ctl = 0
  gru_fused<<<256, NTHR, 0, stream>>>(xs, w_ih, w_hh, bias, bias_n, hslot, ctl, out);
}

// Round 20
// 95151.178 us; speedup vs baseline: 1.5165x; 1.5165x over previous
//
#include <hip/hip_runtime.h>
#include <stdint.h>

typedef unsigned long long u64;
typedef float f32x32 __attribute__((ext_vector_type(32)));
typedef float f32x16 __attribute__((ext_vector_type(16)));

#define T_TOTAL 65536
#define ISZ 256
#define HSZ 512
#define NWORK 16
#define SLICE 32   // HSZ / NWORK
#define NTHR 512   // 8 waves: even 2/SIMD split -> 256-reg budget (R10 lesson)

// LDS skew (word index): +4 words per row -> max 2-way bank aliasing (free).
__device__ __forceinline__ int HSW(int i) { return i + ((i >> 5) << 2); }  // rows of 32
__device__ __forceinline__ int XSW(int i) { return i + ((i >> 4) << 2); }  // rows of 16

struct Ctl { int grank; int chosen; int fastctr; int done; int slowctr; int pad[11]; };

// R20 publish: PLAIN 8B store (write-through vL1 -> XCD L2). R14-proven.
__device__ __forceinline__ void publish_store(u64* p, u64 v) {
  asm volatile("global_store_dwordx2 %0, %1, off" :: "v"(p), "v"(v) : "memory");
}

// R20 poll: nt-only L2 load — NO buffer_inv. R14's round was buffer_inv +
// 2 waits + load executed by all 128 waves on the XCD every round; if 'nt'
// alone keeps slot lines out of vL1, rounds get much cheaper and the global
// L1 thrash disappears. R3 (no nt, no inv) was stale; R14 (nt + inv) worked;
// this isolates which was load-bearing. STICKY FALLBACK tightened to 24
// stale rounds -> R8-proven sc0 RMW poll (bounded regression, correct).
__device__ __forceinline__ u64 poll1_hybrid(u64* p, unsigned sv,
                                            long long& budget, int& sticky) {
  u64 q;
  if (!sticky) {
    for (int i = 0; i < 24; ++i) {
      asm volatile("global_load_dwordx2 %0, %1, off sc0 nt\n\t"
                   "s_waitcnt vmcnt(0)"
                   : "=&v"(q) : "v"(p) : "memory");
      if ((unsigned)(q >> 32) == sv) return q;
    }
    sticky = 1;  // nt loads stale-stuck on this slot: use RMWs from now on
  }
  u64 zero = 0;
  for (;;) {
    asm volatile("global_atomic_add_x2 %0, %1, %2, off sc0\n\t"
                 "s_waitcnt vmcnt(0)"
                 : "=&v"(q) : "v"(p), "v"(zero) : "memory");
    if ((unsigned)(q >> 32) == sv) break;
    if (--budget <= 0) break;
  }
  return q;
}

// ---------------------------------------------------------------------------
// Persistent fused GRU scan, 16 blocks x 512 threads — R14 shell VERBATIM
// (the best structure found: per-thread own-slot poll, publish immediately
// post-butterfly, __syncthreads per step; fire-and-forget stores drain under
// the spin). ONLY change vs R14: poll drops buffer_inv (nt-only), sticky
// threshold 64->24.
//
// Sync: tagged 64-bit slots {tag=version, f32 value}, 16B-padded, parity-2
// ring. FAST mode (16 workers verified on ONE XCD; L2 is the intra-XCD
// coherence point). SLOW fallback: agent-scope acquire/release (R2-proven).
//
// Memory-safety with ONE barrier (B2) per step (R8's proof):
//  - h_lds double-buffered by parity; reuse at s+2 gated by poll(s+2): tag
//    s+2 implies every block passed B2(s+1), i.e. finished iter s reads.
//  - x_lds double-buffered: writes@s+1 after B2(s); reads@s before B2(s).
// Spin fuse bounds worst-case runtime (fail visibly, never wedge).
// ---------------------------------------------------------------------------
__global__ __launch_bounds__(NTHR, 1) void gru_fused(
    const float* __restrict__ xs, const float* __restrict__ w_ih,
    const float* __restrict__ w_hh, const float* __restrict__ bias,
    const float* __restrict__ bias_n, u64* __restrict__ hslot,
    Ctl* __restrict__ ctl, float* __restrict__ out) {
  const int tid = threadIdx.x;
  const int seg = tid & 15;   // K-segment: h[32*seg..+32), x[16*seg..+16)
  const int rg  = tid >> 4;   // unit within slice (0..31)

  __shared__ int s_role, s_fast;
  __shared__ __align__(16) float x_lds[2][320];
  __shared__ __align__(16) float h_lds[2][576];

  // ---- election: verify 16 blocks on one XCD, else agent-scope fallback
  if (tid == 0) {
    unsigned xcc = 0;
    asm volatile("s_getreg_b32 %0, hwreg(HW_REG_XCC_ID)" : "=s"(xcc));
    long long eb = 100000000;
    int rank = __hip_atomic_fetch_add(&ctl->grank, 1, __ATOMIC_RELAXED,
                                      __HIP_MEMORY_SCOPE_AGENT);
    if (rank == 0)
      __hip_atomic_store(&ctl->chosen, (int)xcc + 1, __ATOMIC_RELEASE,
                         __HIP_MEMORY_SCOPE_AGENT);
    int chosen;
    do { chosen = __hip_atomic_load(&ctl->chosen, __ATOMIC_ACQUIRE,
                                    __HIP_MEMORY_SCOPE_AGENT); }
    while (chosen == 0 && --eb > 0);
    int fr = -1;
    if ((int)xcc == chosen - 1)
      fr = __hip_atomic_fetch_add(&ctl->fastctr, 1, __ATOMIC_RELAXED,
                                  __HIP_MEMORY_SCOPE_AGENT);
    __hip_atomic_fetch_add(&ctl->done, 1, __ATOMIC_ACQ_REL,
                           __HIP_MEMORY_SCOPE_AGENT);
    int dn;
    do { dn = __hip_atomic_load(&ctl->done, __ATOMIC_ACQUIRE,
                                __HIP_MEMORY_SCOPE_AGENT); }
    while (dn < (int)gridDim.x && --eb > 0);
    int fc = __hip_atomic_load(&ctl->fastctr, __ATOMIC_ACQUIRE,
                               __HIP_MEMORY_SCOPE_AGENT);
    int fast = (fc >= NWORK && dn >= (int)gridDim.x) ? 1 : 0;
    int role = -1;
    if (fast) {
      if (fr >= 0 && fr < NWORK) role = fr;
    } else {
      int sr = __hip_atomic_fetch_add(&ctl->slowctr, 1, __ATOMIC_RELAXED,
                                      __HIP_MEMORY_SCOPE_AGENT);
      if (sr < NWORK) role = sr;
    }
    s_role = role; s_fast = fast;
  }
  __syncthreads();
  const int role = s_role;   // uniform per block
  const int fast = s_fast;
  if (role < 0) return;      // whole block exits together

  // ---- weights into registers (ext_vector, static indexing; R8-proven) ----
  const int myunit = role * SLICE + rg;
  f32x32 wh0, wh1, wh2;
  f32x16 wi0, wi1, wi2;
  {
    const float* h0 = w_hh + (size_t)(0 * HSZ + myunit) * HSZ + seg * 32;
    const float* h1 = w_hh + (size_t)(1 * HSZ + myunit) * HSZ + seg * 32;
    const float* h2 = w_hh + (size_t)(2 * HSZ + myunit) * HSZ + seg * 32;
#pragma unroll
    for (int u = 0; u < 8; ++u) {
      float4 a = *(const float4*)(h0 + u * 4);
      float4 b = *(const float4*)(h1 + u * 4);
      float4 c = *(const float4*)(h2 + u * 4);
      wh0[u*4+0]=a.x; wh0[u*4+1]=a.y; wh0[u*4+2]=a.z; wh0[u*4+3]=a.w;
      wh1[u*4+0]=b.x; wh1[u*4+1]=b.y; wh1[u*4+2]=b.z; wh1[u*4+3]=b.w;
      wh2[u*4+0]=c.x; wh2[u*4+1]=c.y; wh2[u*4+2]=c.z; wh2[u*4+3]=c.w;
    }
    const float* i0 = w_ih + (size_t)(0 * HSZ + myunit) * ISZ + seg * 16;
    const float* i1 = w_ih + (size_t)(1 * HSZ + myunit) * ISZ + seg * 16;
    const float* i2 = w_ih + (size_t)(2 * HSZ + myunit) * ISZ + seg * 16;
#pragma unroll
    for (int u = 0; u < 4; ++u) {
      float4 a = *(const float4*)(i0 + u * 4);
      float4 b = *(const float4*)(i1 + u * 4);
      float4 c = *(const float4*)(i2 + u * 4);
      wi0[u*4+0]=a.x; wi0[u*4+1]=a.y; wi0[u*4+2]=a.z; wi0[u*4+3]=a.w;
      wi1[u*4+0]=b.x; wi1[u*4+1]=b.y; wi1[u*4+2]=b.z; wi1[u*4+3]=b.w;
      wi2[u*4+0]=c.x; wi2[u*4+1]=c.y; wi2[u*4+2]=c.z; wi2[u*4+3]=c.w;
    }
  }
  const float br  = bias[myunit];
  const float bz  = bias[HSZ + myunit];
  const float bnn = bias[2 * HSZ + myunit];
  const float bn2 = bias_n[myunit];

  // prologue: x[0] -> LDS buf0; xreg holds x[1]
  float4 xreg{};
  if (tid < 64) {
    float4 t0 = *(const float4*)(xs + tid * 4);
    *(float4*)&x_lds[0][XSW(tid * 4)] = t0;
    xreg = *(const float4*)(xs + (size_t)ISZ + tid * 4);
  }
  __syncthreads();

  long long budget = 20000000;  // spin fuse (fail visibly, never wedge)
  int sticky = 0;               // per-thread: nt-load poll until proven stale

  for (int s = 0; s < T_TOTAL; ++s) {
    const int cur = s & 1, nxt = cur ^ 1;

    // x[s+1] prefetch (off-chain; HBM latency hides under the h-wait).
    float4 xpf;
    if (tid < 64) {
      int srow = (s + 1 < T_TOTAL) ? (s + 1) : s;
      xpf = *(const float4*)(xs + (size_t)srow * ISZ + tid * 4);
    }

    // Input-side gate dots (independent of h). a3 = hidden-side n, separate.
    float a0 = 0.f, a1 = 0.f, a2 = 0.f, a3 = 0.f;
#pragma unroll
    for (int u = 0; u < 4; ++u) {
      float4 xv = *(const float4*)&x_lds[cur][XSW(seg * 16 + u * 4)];
      a0 += wi0[u*4+0]*xv.x + wi0[u*4+1]*xv.y + wi0[u*4+2]*xv.z + wi0[u*4+3]*xv.w;
      a1 += wi1[u*4+0]*xv.x + wi1[u*4+1]*xv.y + wi1[u*4+2]*xv.z + wi1[u*4+3]*xv.w;
      a2 += wi2[u*4+0]*xv.x + wi2[u*4+1]*xv.y + wi2[u*4+2]*xv.z + wi2[u*4+3]*xv.w;
    }
    if (tid < 64) *(float4*)&x_lds[nxt][XSW(tid * 4)] = xpf;  // after B2(s-1)

    // Poll h version s (1 slot/thread, 16B padded).
    u64* sb = hslot + (size_t)cur * (HSZ * 2);
    u64 q0;
    if (fast) {
      q0 = poll1_hybrid(&sb[2 * tid], (unsigned)s, budget, sticky);
    } else {
      do {
        q0 = __hip_atomic_load(&sb[2 * tid], __ATOMIC_ACQUIRE,
                               __HIP_MEMORY_SCOPE_AGENT);
      } while ((unsigned)(q0 >> 32) != (unsigned)s && --budget > 0);
    }
    h_lds[cur][HSW(tid)] = __uint_as_float((unsigned)q0);
    __syncthreads();  // B2: h + x[nxt] staged; the only barrier per step

    // Hidden-side dots (critical chain): 3 rows x 32-wide segment.
#pragma unroll
    for (int u = 0; u < 8; ++u) {
      float4 hv = *(const float4*)&h_lds[cur][HSW(seg * 32 + u * 4)];
      a0 += wh0[u*4+0]*hv.x + wh0[u*4+1]*hv.y + wh0[u*4+2]*hv.z + wh0[u*4+3]*hv.w;
      a1 += wh1[u*4+0]*hv.x + wh1[u*4+1]*hv.y + wh1[u*4+2]*hv.z + wh1[u*4+3]*hv.w;
      a3 += wh2[u*4+0]*hv.x + wh2[u*4+1]*hv.y + wh2[u*4+2]*hv.z + wh2[u*4+3]*hv.w;
    }
#pragma unroll
    for (int p = 0; p < 4; ++p) {
      int m = 1 << p;
      a0 += __shfl_xor(a0, m, 64);
      a1 += __shfl_xor(a1, m, 64);
      a2 += __shfl_xor(a2, m, 64);
      a3 += __shfl_xor(a3, m, 64);
    }

    // Epilogue + publish (chain edge first), then out store.
    if (seg == 0) {
      float r  = 1.f / (1.f + __expf(-(br + a0)));
      float z  = 1.f / (1.f + __expf(-(bz + a1)));
      float tv = bnn + a2 + r * (a3 + bn2);
      float nn = 1.f - 2.f / (__expf(2.f * tv) + 1.f);  // tanh, exact limits
      float hold = h_lds[cur][HSW(myunit)];
      float hnew = nn + z * (hold - nn);
      u64 pw = ((u64)(unsigned)(s + 1) << 32) | (u64)__float_as_uint(hnew);
      u64* pp = &hslot[(size_t)nxt * (HSZ * 2) + 2 * myunit];
      if (fast)
        publish_store(pp, pw);
      else
        __hip_atomic_store(pp, pw, __ATOMIC_RELEASE, __HIP_MEMORY_SCOPE_AGENT);
      out[(size_t)HSZ + (size_t)s * HSZ + myunit] = hnew;
      if (s == T_TOTAL - 1) out[myunit] = hnew;
    }
  }
}

// ---------------------------------------------------------------------------
extern "C" void kernel_launch(void* const* d_in, const int* in_sizes, int n_in,
                              void* d_out, int out_size, void* d_ws, size_t ws_size,
                              hipStream_t stream) {
  const float* xs     = (const float*)d_in[0];
  const float* w_ih   = (const float*)d_in[1];
  const float* w_hh   = (const float*)d_in[2];
  const float* bias   = (const float*)d_in[3];
  const float* bias_n = (const float*)d_in[4];
  float* out   = (float*)d_out;
  u64*   hslot = (u64*)d_ws;                    // [2][512] padded slots = 16 KB
  Ctl*   ctl   = (Ctl*)((char*)d_ws + 16384);   // election control

  hipMemsetAsync(d_ws, 0, 16384 + 256, stream); // tags=0 => h_0 = 0; ctl = 0
  gru_fused<<<256, NTHR, 0, stream>>>(xs, w_ih, w_hh, bias, bias_n, hslot, ctl, out);
}